// Round 12
// baseline (112.807 us; speedup 1.0000x reference)
//
#include <hip/hip_runtime.h>
#include <math.h>

#define NRAYS 8192
#define NS 512
#define HID 32
#define SPL 4   // samples per lane; 2 waves per ray: 2*64*4 = 512 = NS

typedef float f32x2 __attribute__((ext_vector_type(2)));

// 2 waves per ray; lane owns 4 contiguous samples (packed {s0,s1},{s2,s3}).
// Weights live in REGISTERS, lane-distributed: lane j (=lane&31) holds hidden
// unit j's {A_j, B_j} (layer-1 collapsed to affine in ts) and {Wc[j][*], Wd[j]}.
// The unrolled j-loop broadcasts them via v_readlane (no LDS, no lgkmcnt in the
// hot loop). LDS is used only for the tiny cross-wave cumsum/partial exchange.
__global__ __launch_bounds__(256, 8) void render_kernel(
    const float* __restrict__ o_, const float* __restrict__ d_,
    const float* __restrict__ aabb, const float* __restrict__ u_,
    const float* __restrict__ W1, const float* __restrict__ b1,
    const float* __restrict__ Wc, const float* __restrict__ bc,
    const float* __restrict__ Wd, const float* __restrict__ bd,
    float* __restrict__ out)
{
    __shared__ float wtot[2][2];    // [ray-slot][half] cumsum totals
    __shared__ float4 wpart[2][2];  // [ray-slot][half] partial RGBA

    const int tid  = threadIdx.x;
    const int lane = tid & 63;
    const int wave = tid >> 6;   // 0..3
    const int pair = wave >> 1;  // ray slot within block
    const int half = wave & 1;   // which 256-sample half of the ray
    const int ray  = (blockIdx.x << 1) + pair;

    // ---- lane-distributed weight load (unconditional, coalesced, L2-hot) ----
    const int j0 = lane & 31;
    const float w1x = W1[0 * HID + j0];
    const float w1y = W1[1 * HID + j0];
    const float w1z = W1[2 * HID + j0];
    const float b1j = b1[j0];
    const float wrj = Wc[j0 * 3 + 0];
    const float wgj = Wc[j0 * 3 + 1];
    const float wbj = Wc[j0 * 3 + 2];
    const float wdj = Wd[j0];
    const float bc0 = bc[0], bc1 = bc[1], bc2 = bc[2], bd0 = bd[0];

    const float ox = o_[ray * 3 + 0], oy = o_[ray * 3 + 1], oz = o_[ray * 3 + 2];
    const float dx = d_[ray * 3 + 0], dy = d_[ray * 3 + 1], dz = d_[ray * 3 + 2];
    const float lox = aabb[0], loy = aabb[1], loz = aabb[2];
    const float hix = aabb[3], hiy = aabb[4], hiz = aabb[5];

    // Slab test (plain IEEE division; +-inf handled like the reference).
    float t1 = (lox - ox) / dx, t2 = (hix - ox) / dx;
    float tnear = fminf(t1, t2), tfar = fmaxf(t1, t2);
    t1 = (loy - oy) / dy; t2 = (hiy - oy) / dy;
    tnear = fmaxf(tnear, fminf(t1, t2)); tfar = fminf(tfar, fmaxf(t1, t2));
    t1 = (loz - oz) / dz; t2 = (hiz - oz) / dz;
    tnear = fmaxf(tnear, fminf(t1, t2)); tfar = fminf(tfar, fmaxf(t1, t2));
    tnear = fmaxf(tnear, 0.0f);

    const bool active = (tnear < tfar);   // uniform across the ray's 2 waves

    float sd[SPL], csum[SPL], colR[SPL], colG[SPL], colB[SPL];
    float Lsc = 0.0f, cum = 0.0f, T = 0.0f;

    // ---- phase 1: MLP, density, local+wave cumsum (no barriers, no LDS) ----
    if (active) {
        const float dnorm = sqrtf(dx * dx + dy * dy + dz * dz);
        const float dt = (tfar - tnear) * (1.0f / (float)NS);
        const float sx = 2.0f / (hix - lox);
        const float sy = 2.0f / (hiy - loy);
        const float sz = 2.0f / (hiz - loz);

        // ndc(ts) = c + g*ts per axis; layer-1 pre-act h_j = A_j + B_j*ts
        const float cx = (ox - lox) * sx - 1.0f, gx = dx * sx;
        const float cy = (oy - loy) * sy - 1.0f, gy = dy * sy;
        const float cz = (oz - loz) * sz - 1.0f, gz = dz * sz;
        const float Av = fmaf(cx, w1x, fmaf(cy, w1y, fmaf(cz, w1z, b1j)));
        const float Bv = fmaf(gx, w1x, fmaf(gy, w1y, gz * w1z));

        const int t0 = (half << 8) + (lane << 2);
        const float* __restrict__ urow = u_ + (size_t)ray * NS;
        const float4 ua = *reinterpret_cast<const float4*>(urow + t0);
        const float unext = (t0 + 4 < NS) ? urow[t0 + 4] : 0.0f;
        float us[5] = {ua.x, ua.y, ua.z, ua.w, unext};

        float tsv[SPL], delta[SPL];
        #pragma unroll
        for (int s = 0; s < SPL; ++s) {
            const int t = t0 + s;
            tsv[s] = fmaf(dt, (float)t + us[s], tnear);
            const float dl = (t == NS - 1) ? (tfar + 1.0f) - tsv[s]     // BOOSTER=1
                                           : dt * (1.0f + us[s + 1] - us[s]);
            delta[s] = dl * dnorm;
        }
        const f32x2 ts01 = {tsv[0], tsv[1]};
        const f32x2 ts23 = {tsv[2], tsv[3]};

        f32x2 cr01 = {bc0, bc0}, cr23 = {bc0, bc0};
        f32x2 cg01 = {bc1, bc1}, cg23 = {bc1, bc1};
        f32x2 cb01 = {bc2, bc2}, cb23 = {bc2, bc2};
        f32x2 dd01 = {bd0, bd0}, dd23 = {bd0, bd0};

        #pragma unroll
        for (int j = 0; j < HID; ++j) {
            // v_readlane broadcasts: wave-uniform scalars, no memory pipe
            const float Aj = __int_as_float(__builtin_amdgcn_readlane(__float_as_int(Av), j));
            const float Bj = __int_as_float(__builtin_amdgcn_readlane(__float_as_int(Bv), j));
            const float wr = __int_as_float(__builtin_amdgcn_readlane(__float_as_int(wrj), j));
            const float wg = __int_as_float(__builtin_amdgcn_readlane(__float_as_int(wgj), j));
            const float wb = __int_as_float(__builtin_amdgcn_readlane(__float_as_int(wbj), j));
            const float wd = __int_as_float(__builtin_amdgcn_readlane(__float_as_int(wdj), j));
            const f32x2 A2 = {Aj, Aj}, B2 = {Bj, Bj};
            const f32x2 h01 = __builtin_elementwise_max(
                __builtin_elementwise_fma(ts01, B2, A2), (f32x2){0.0f, 0.0f});
            const f32x2 h23 = __builtin_elementwise_max(
                __builtin_elementwise_fma(ts23, B2, A2), (f32x2){0.0f, 0.0f});
            cr01 = __builtin_elementwise_fma(h01, (f32x2){wr, wr}, cr01);
            cr23 = __builtin_elementwise_fma(h23, (f32x2){wr, wr}, cr23);
            cg01 = __builtin_elementwise_fma(h01, (f32x2){wg, wg}, cg01);
            cg23 = __builtin_elementwise_fma(h23, (f32x2){wg, wg}, cg23);
            cb01 = __builtin_elementwise_fma(h01, (f32x2){wb, wb}, cb01);
            cb23 = __builtin_elementwise_fma(h23, (f32x2){wb, wb}, cb23);
            dd01 = __builtin_elementwise_fma(h01, (f32x2){wd, wd}, dd01);
            dd23 = __builtin_elementwise_fma(h23, (f32x2){wd, wd}, dd23);
        }

        const float ddv[SPL] = {dd01.x, dd01.y, dd23.x, dd23.y};
        const float crv[SPL] = {cr01.x, cr01.y, cr23.x, cr23.y};
        const float cgv[SPL] = {cg01.x, cg01.y, cg23.x, cg23.y};
        const float cbv[SPL] = {cb01.x, cb01.y, cb23.x, cb23.y};

        cum = 0.0f;
        #pragma unroll
        for (int s = 0; s < SPL; ++s) {
            const float dd = ddv[s];
            const float dens = fmaxf(dd, 0.0f) + __logf(1.0f + __expf(-fabsf(dd)));
            sd[s] = dens * delta[s];
            cum += sd[s];
            csum[s] = cum;
            colR[s] = __builtin_amdgcn_rcpf(1.0f + __expf(-crv[s]));
            colG[s] = __builtin_amdgcn_rcpf(1.0f + __expf(-cgv[s]));
            colB[s] = __builtin_amdgcn_rcpf(1.0f + __expf(-cbv[s]));
        }

        // Kogge-Stone inclusive scan of lane totals within the wave
        Lsc = cum;
        #pragma unroll
        for (int off = 1; off < 64; off <<= 1) {
            const float v = __shfl_up(Lsc, off);
            Lsc += (lane >= off) ? v : 0.0f;
        }
        T = __shfl(Lsc, 63);   // wave total
    }

    if (lane == 0) wtot[pair][half] = T;   // inactive rays publish 0
    __syncthreads();

    // ---- phase 2: global prefix, weights, accumulate, wave partials ----
    float4 partial = make_float4(0.0f, 0.0f, 0.0f, 0.0f);
    if (active) {
        const float E = (half ? wtot[pair][0] : 0.0f) + (Lsc - cum);
        const float e0 = __expf(-E);
        float eprev = e0;
        float aR = 0.0f, aG = 0.0f, aB = 0.0f;
        #pragma unroll
        for (int s = 0; s < SPL; ++s) {
            const float ecur = __expf(-(E + csum[s]));
            const float w = eprev - ecur;    // trans*(1-exp(-sd))
            eprev = ecur;
            aR = fmaf(w, colR[s], aR);
            aG = fmaf(w, colG[s], aG);
            aB = fmaf(w, colB[s], aB);
        }
        float aA = e0 - eprev;               // telescoped per-lane alpha

        #pragma unroll
        for (int off = 32; off; off >>= 1) {
            aR += __shfl_xor(aR, off);
            aG += __shfl_xor(aG, off);
            aB += __shfl_xor(aB, off);
            aA += __shfl_xor(aA, off);
        }
        partial = make_float4(aR, aG, aB, aA);
    }

    if (lane == 0) wpart[pair][half] = partial;
    __syncthreads();

    if (half == 0 && lane == 0) {
        const float4 p0 = wpart[pair][0];
        const float4 p1 = wpart[pair][1];
        reinterpret_cast<float4*>(out)[ray] =
            make_float4(p0.x + p1.x, p0.y + p1.y, p0.z + p1.z, p0.w + p1.w);
    }
}

extern "C" void kernel_launch(void* const* d_in, const int* in_sizes, int n_in,
                              void* d_out, int out_size, void* d_ws, size_t ws_size,
                              hipStream_t stream) {
    const float* o_   = (const float*)d_in[0];
    const float* d_   = (const float*)d_in[1];
    const float* aabb = (const float*)d_in[2];
    const float* u_   = (const float*)d_in[3];
    const float* W1   = (const float*)d_in[4];
    const float* b1   = (const float*)d_in[5];
    const float* Wc   = (const float*)d_in[6];
    const float* bc   = (const float*)d_in[7];
    const float* Wd   = (const float*)d_in[8];
    const float* bd   = (const float*)d_in[9];
    float* out = (float*)d_out;

    // 2 rays per block (2 waves per ray) -> 4096 blocks, 16384 waves
    render_kernel<<<NRAYS / 2, 256, 0, stream>>>(o_, d_, aabb, u_, W1, b1, Wc, bc, Wd, bd, out);
}

// Round 13
// 99.828 us; speedup vs baseline: 1.1300x; 1.1300x over previous
//
#include <hip/hip_runtime.h>
#include <math.h>

#define NRAYS 8192
#define NS 512
#define HID 32
#define SPL 8   // samples per lane; 1 wave per ray

typedef float f32x2 __attribute__((ext_vector_type(2)));

// One wave per ray. The MLP is piecewise-linear in t: h_j(t)=relu(A_j+B_j*t),
// so out4(t) = bias4 + P4(seg) + Q4(seg)*t between ReLU breakpoints.
// Phase A (per ray): lane j computes (A_j,B_j), breakpoint tb_j=-A_j/B_j,
// event delta (+-(A_j,B_j)*w4_j), bitonic-sorts events by tb (key+src only),
// gathers payload via ds_bpermute, prefix-sums 8 channels, stores 33 segments
// (key, P4, Q4) in LDS. Phase C (per sample): binary-search + forward-walk the
// segment (samples and keys both ascending), 2x ds_read_b128, 2 pk_fma eval.
__global__ __launch_bounds__(256) void render_kernel(
    const float* __restrict__ o_, const float* __restrict__ d_,
    const float* __restrict__ aabb, const float* __restrict__ u_,
    const float* __restrict__ W1, const float* __restrict__ b1,
    const float* __restrict__ Wc, const float* __restrict__ bc,
    const float* __restrict__ Wd, const float* __restrict__ bd,
    float* __restrict__ out)
{
    __shared__ float  keyA[4][68];   // [wave][0..32 keys, 33..67 = +inf pad]
    __shared__ float4 cPA[4][33];    // segment P4 (color R,G,B and density pre-act)
    __shared__ float4 cQA[4][33];    // segment Q4

    const int tid  = threadIdx.x;
    const int lane = tid & 63;
    const int wv   = tid >> 6;         // wave in block = ray slot
    const int id   = lane & 31;        // hidden unit index (both halves mirror)
    const int ray  = (blockIdx.x << 2) + wv;

    // ---- lane-distributed weight load (coalesced, L2-hot) ----
    const float w1x = W1[0 * HID + id];
    const float w1y = W1[1 * HID + id];
    const float w1z = W1[2 * HID + id];
    const float b1j = b1[id];
    const float wr  = Wc[id * 3 + 0];
    const float wg  = Wc[id * 3 + 1];
    const float wb  = Wc[id * 3 + 2];
    const float wd  = Wd[id];
    const float bc0 = bc[0], bc1 = bc[1], bc2 = bc[2], bd0 = bd[0];

    const float ox = o_[ray * 3 + 0], oy = o_[ray * 3 + 1], oz = o_[ray * 3 + 2];
    const float dx = d_[ray * 3 + 0], dy = d_[ray * 3 + 1], dz = d_[ray * 3 + 2];
    const float lox = aabb[0], loy = aabb[1], loz = aabb[2];
    const float hix = aabb[3], hiy = aabb[4], hiz = aabb[5];

    // Slab test (plain IEEE division; +-inf handled like the reference).
    float t1 = (lox - ox) / dx, t2 = (hix - ox) / dx;
    float tnear = fminf(t1, t2), tfar = fmaxf(t1, t2);
    t1 = (loy - oy) / dy; t2 = (hiy - oy) / dy;
    tnear = fmaxf(tnear, fminf(t1, t2)); tfar = fminf(tfar, fmaxf(t1, t2));
    t1 = (loz - oz) / dz; t2 = (hiz - oz) / dz;
    tnear = fmaxf(tnear, fminf(t1, t2)); tfar = fminf(tfar, fmaxf(t1, t2));
    tnear = fmaxf(tnear, 0.0f);

    const bool active = (tnear < tfar);   // wave-uniform

    // ================= Phase A: build piecewise-linear segments =================
    if (active) {
        const float sx = 2.0f / (hix - lox);
        const float sy = 2.0f / (hiy - loy);
        const float sz = 2.0f / (hiz - loz);
        const float cx = (ox - lox) * sx - 1.0f, gx = dx * sx;
        const float cy = (oy - loy) * sy - 1.0f, gy = dy * sy;
        const float cz = (oz - loz) * sz - 1.0f, gz = dz * sz;

        const float A = fmaf(cx, w1x, fmaf(cy, w1y, fmaf(cz, w1z, b1j)));
        const float B = fmaf(gx, w1x, fmaf(gy, w1y, gz * w1z));

        float dP[4], dQ[4];
        dP[0] = A * wr; dP[1] = A * wg; dP[2] = A * wb; dP[3] = A * wd;
        dQ[0] = B * wr; dQ[1] = B * wg; dQ[2] = B * wb; dQ[3] = B * wd;

        // base state at t = tnear
        const bool act0 = fmaf(B, tnear, A) > 0.0f;
        float base[8];
        #pragma unroll
        for (int c = 0; c < 4; ++c) {
            base[c]     = act0 ? dP[c] : 0.0f;
            base[c + 4] = act0 ? dQ[c] : 0.0f;
        }
        #pragma unroll
        for (int m = 1; m <= 16; m <<= 1) {
            #pragma unroll
            for (int c = 0; c < 8; ++c) base[c] += __shfl_xor(base[c], m);
        }

        // event (breakpoint inside (tnear, tfar))
        const float tb = -A / B;                     // inf/NaN if B==0
        const bool ev = (tb > tnear) && (tb < tfar) && (fabsf(tb) < 1e30f);
        const float sgn = (B > 0.0f) ? 1.0f : -1.0f;
        float key = ev ? tb : 3e38f;
        float e[8];
        #pragma unroll
        for (int c = 0; c < 4; ++c) {
            e[c]     = ev ? sgn * dP[c] : 0.0f;
            e[c + 4] = ev ? sgn * dQ[c] : 0.0f;
        }
        int src = lane;

        // bitonic sort (key, src) ascending within each 32-lane half
        #pragma unroll
        for (int k = 2; k <= 32; k <<= 1) {
            #pragma unroll
            for (int j = k >> 1; j >= 1; j >>= 1) {
                const float pkey = __shfl_xor(key, j);
                const int   psrc = __shfl_xor(src, j);
                const bool up    = ((id & k) == 0);
                const bool lower = ((id & j) == 0);
                const bool pless = (pkey < key) || ((pkey == key) && (psrc < src));
                const bool wantMin = (lower == up);
                const bool take = wantMin ? pless : !pless;
                key = take ? pkey : key;
                src = take ? psrc : src;
            }
        }

        // gather payload from pre-sort source lane
        float se[8];
        #pragma unroll
        for (int c = 0; c < 8; ++c)
            se[c] = __int_as_float(__builtin_amdgcn_ds_bpermute(src << 2, __float_as_int(e[c])));

        // inclusive prefix over sorted events (within each 32-half)
        #pragma unroll
        for (int off = 1; off < 32; off <<= 1) {
            #pragma unroll
            for (int c = 0; c < 8; ++c) {
                const float v = __shfl_up(se[c], off);
                se[c] += (id >= off) ? v : 0.0f;
            }
        }

        // write segment table (lower half only; upper half mirrors)
        if (lane < 32) {
            keyA[wv][id + 1] = key;
            cPA[wv][id + 1] = make_float4(base[0] + se[0], base[1] + se[1],
                                          base[2] + se[2], base[3] + se[3]);
            cQA[wv][id + 1] = make_float4(base[4] + se[4], base[5] + se[5],
                                          base[6] + se[6], base[7] + se[7]);
        }
        if (lane == 0) {
            keyA[wv][0] = -3e38f;
            cPA[wv][0] = make_float4(base[0], base[1], base[2], base[3]);
            cQA[wv][0] = make_float4(base[4], base[5], base[6], base[7]);
        }
        if (lane < 35) keyA[wv][33 + lane] = 3e38f;   // pad 33..67
    }

    __syncthreads();   // all waves reach this (branch above is wave-uniform)

    // ================= Phase C: per-sample evaluation =================
    float4 res = make_float4(0.0f, 0.0f, 0.0f, 0.0f);

    if (active) {
        const float dnorm = sqrtf(dx * dx + dy * dy + dz * dz);
        const float dt = (tfar - tnear) * (1.0f / (float)NS);

        const int base_t = lane * SPL;
        const float* __restrict__ urow = u_ + (size_t)ray * NS + base_t;
        const float4 uaq = *reinterpret_cast<const float4*>(urow);
        const float4 ubq = *reinterpret_cast<const float4*>(urow + 4);
        float us[9];
        us[0] = uaq.x; us[1] = uaq.y; us[2] = uaq.z; us[3] = uaq.w;
        us[4] = ubq.x; us[5] = ubq.y; us[6] = ubq.z; us[7] = ubq.w;
        us[8] = __shfl_down(uaq.x, 1);   // u[8(i+1)]; lane 63 unused (tfar branch)

        float tsv[SPL], delta[SPL];
        #pragma unroll
        for (int s = 0; s < SPL; ++s) {
            const int t = base_t + s;
            tsv[s] = fmaf(dt, (float)t + us[s], tnear);
            const float dl = (t == NS - 1) ? (tfar + 1.0f) - tsv[s]   // BOOSTER=1
                                           : dt * (1.0f + us[s + 1] - us[s]);
            delta[s] = dl * dnorm;
        }

        const float* keys = &keyA[wv][0];

        // binary search for first sample's segment: max k with keys[k] <= t
        int k = 0;
        {
            const float t0v = tsv[0];
            if (keys[k + 32] <= t0v) k += 32;
            if (keys[k + 16] <= t0v) k += 16;
            if (keys[k + 8]  <= t0v) k += 8;
            if (keys[k + 4]  <= t0v) k += 4;
            if (keys[k + 2]  <= t0v) k += 2;
            if (keys[k + 1]  <= t0v) k += 1;
        }

        float sd[SPL], csum[SPL], cR[SPL], cG[SPL], cB[SPL];
        float cum = 0.0f;
        #pragma unroll
        for (int s = 0; s < SPL; ++s) {
            const float t = tsv[s];
            while (keys[k + 1] <= t) ++k;     // pads (+inf) terminate; k <= 32
            const float4 P = cPA[wv][k];
            const float4 Q = cQA[wv][k];
            const float crv = fmaf(Q.x, t, P.x) + bc0;
            const float cgv = fmaf(Q.y, t, P.y) + bc1;
            const float cbv = fmaf(Q.z, t, P.z) + bc2;
            const float ddv = fmaf(Q.w, t, P.w) + bd0;
            const float dens = fmaxf(ddv, 0.0f) + __logf(1.0f + __expf(-fabsf(ddv)));
            sd[s] = dens * delta[s];
            cum += sd[s];
            csum[s] = cum;
            cR[s] = __builtin_amdgcn_rcpf(1.0f + __expf(-crv));
            cG[s] = __builtin_amdgcn_rcpf(1.0f + __expf(-cgv));
            cB[s] = __builtin_amdgcn_rcpf(1.0f + __expf(-cbv));
        }

        // Kogge-Stone inclusive scan over lane totals (64 lanes)
        float L = cum;
        #pragma unroll
        for (int off = 1; off < 64; off <<= 1) {
            const float v = __shfl_up(L, off);
            L += (lane >= off) ? v : 0.0f;
        }
        const float E = L - cum;   // exclusive prefix for this lane

        float aR = 0.0f, aG = 0.0f, aB = 0.0f;
        const float e0 = __expf(-E);
        float eprev = e0;
        #pragma unroll
        for (int s = 0; s < SPL; ++s) {
            const float ecur = __expf(-(E + csum[s]));
            const float w = eprev - ecur;    // trans*(1-exp(-sd))
            eprev = ecur;
            aR = fmaf(w, cR[s], aR);
            aG = fmaf(w, cG[s], aG);
            aB = fmaf(w, cB[s], aB);
        }
        float aA = e0 - eprev;               // telescoped per-lane alpha

        #pragma unroll
        for (int off = 32; off; off >>= 1) {
            aR += __shfl_xor(aR, off);
            aG += __shfl_xor(aG, off);
            aB += __shfl_xor(aB, off);
            aA += __shfl_xor(aA, off);
        }
        res = make_float4(aR, aG, aB, aA);
    }

    if (lane == 0) {
        reinterpret_cast<float4*>(out)[ray] = res;
    }
}

extern "C" void kernel_launch(void* const* d_in, const int* in_sizes, int n_in,
                              void* d_out, int out_size, void* d_ws, size_t ws_size,
                              hipStream_t stream) {
    const float* o_   = (const float*)d_in[0];
    const float* d_   = (const float*)d_in[1];
    const float* aabb = (const float*)d_in[2];
    const float* u_   = (const float*)d_in[3];
    const float* W1   = (const float*)d_in[4];
    const float* b1   = (const float*)d_in[5];
    const float* Wc   = (const float*)d_in[6];
    const float* bc   = (const float*)d_in[7];
    const float* Wd   = (const float*)d_in[8];
    const float* bd   = (const float*)d_in[9];
    float* out = (float*)d_out;

    // 1 wave per ray, 4 rays per block -> 2048 blocks
    render_kernel<<<NRAYS / 4, 256, 0, stream>>>(o_, d_, aabb, u_, W1, b1, Wc, bc, Wd, bd, out);
}